// Round 2
// baseline (530.526 us; speedup 1.0000x reference)
//
#include <hip/hip_runtime.h>

// out[a,bc,d,g] = (1/3) * sum_{e,f} T1[a,bc,d,e,f] * T2[bc,e,f,g]
// A=4, BC=786432; T1 slab 27 f32, T2 slab 27 f32, out slab 9 f32.
// ~538 MB irreducible traffic -> ~85us floor at 6.3 TB/s achievable.
//
// v3: persistent blocks (512 = 2/CU), double-buffered LDS input tiles,
// counted s_waitcnt vmcnt(N) + raw s_barrier so prefetch loads stay in
// flight across the barrier (no vmcnt(0) drain per tile). Per-wave VMEM
// accounting: wave w issues L chunks/tile (w<3: 9, w3: 8) and S stores/tile
// (w0: 3, else 2); at the wait for tile i the allowed residue is
// S (stores of tile i-1) + L (loads of tile i+1).

#define A_        4
#define BC_       786432
#define TILE_     64
#define NTHREADS  256
#define NBLOCKS   512
#define TPB       24              // tiles per block = (BC_/TILE_)/NBLOCKS

#define SEG_BYTES    6912         // TILE_*27*4 per staged segment
#define CHUNK_BYTES  1024         // 64 lanes * 16B
#define FULL_CHUNKS  6
#define TAIL_LANES   48           // 768B tail chunk
#define NCHUNK       35           // 5 segments * 7 chunks

#define T1_A_BYTES     84934656u  // BC_*27*4
#define OUT_A_STRIDE4  1769472    // BC_*9/4
#define OUT_TILE4      144        // TILE_*9/4

#define BUF_FLOATS   8640         // one input buffer (4 T1 segs + 1 T2 seg)
#define OUT_OFF      (2 * BUF_FLOATS)
#define SMEM_FLOATS  (2 * BUF_FLOATS + 2304)   // 78336 B -> 2 blocks/CU

#define WAITV(n) asm volatile("s_waitcnt vmcnt(" #n ")" ::: "memory")
#define CFENCE() asm volatile("" ::: "memory")

__device__ __forceinline__ void load_lds16(const void* g, void* l) {
    __builtin_amdgcn_global_load_lds(
        (const __attribute__((address_space(1))) void*)g,
        (__attribute__((address_space(3))) void*)l, 16, 0, 0);
}

// Issue this wave's chunk loads for one tile into `buf`.
// wave w handles chunks [9w, min(35, 9w+9)): waves 0-2 -> 9, wave 3 -> 8.
__device__ __forceinline__ void stage_tile(const char* t1base, const char* t2base,
                                           int tile, float* buf,
                                           int wave, int lane) {
    const char* t1b = t1base + (size_t)tile * SEG_BYTES;
    const char* t2b = t2base + (size_t)tile * SEG_BYTES;
    char* lds0 = (char*)buf;
    const int c0 = wave * 9;
    const int c1 = (c0 + 9 < NCHUNK) ? (c0 + 9) : NCHUNK;
    for (int c = c0; c < c1; ++c) {
        const int s = c / 7;              // segment 0..4
        const int k = c - s * 7;          // chunk within segment 0..6
        const char* gseg = (s < 4) ? (t1b + (size_t)s * T1_A_BYTES) : t2b;
        const char* gsrc = gseg + k * CHUNK_BYTES + lane * 16;
        char*       ldst = lds0 + s * SEG_BYTES + k * CHUNK_BYTES;
        if (k < FULL_CHUNKS) {
            load_lds16(gsrc, ldst);            // full 1 KiB chunk
        } else if (lane < TAIL_LANES) {
            load_lds16(gsrc, ldst);            // 768 B tail (one vmcnt op/wave)
        }
    }
}

__global__ __launch_bounds__(NTHREADS, 2)
void prod_einsum_kernel(const float* __restrict__ T1,
                        const float* __restrict__ T2,
                        float* __restrict__ Out) {
    __shared__ float smem[SMEM_FLOATS];
    float4* Outv = (float4*)Out;

    const int tid  = threadIdx.x;
    const int lane = tid & 63;
    const int wave = tid >> 6;
    const int a    = wave;
    const int l    = lane;
    const int t0   = blockIdx.x * TPB;

    const char* t1base = (const char*)T1;
    const char* t2base = (const char*)T2;

    // Prologue: stage tile 0 into buffer 0.
    stage_tile(t1base, t2base, t0, smem, wave, lane);

    for (int i = 0; i < TPB; ++i) {
        float* bufc = smem + (i & 1) * BUF_FLOATS;

        // Issue prefetch of tile i+1 into the alternate buffer. Safe: all
        // waves passed the previous iteration's staging barrier, so tile
        // i-1's LDS reads of that buffer are retired.
        if (i + 1 < TPB)
            stage_tile(t1base, t2base, t0 + i + 1,
                       smem + ((i + 1) & 1) * BUF_FLOATS, wave, lane);

        // Wait until THIS wave's tile-i chunks have landed; leave tile i+1's
        // loads and tile i-1's stores in flight (exact per-wave residues).
        if (i == 0) {
            if (i + 1 < TPB) { if (wave == 3) WAITV(8); else WAITV(9); }
            else             { WAITV(0); }
        } else if (i + 1 < TPB) {
            if (wave == 0)      WAITV(12);   // 3 stores + 9 loads
            else if (wave == 3) WAITV(10);   // 2 stores + 8 loads
            else                WAITV(11);   // 2 stores + 9 loads
        } else {
            if (wave == 0) WAITV(3); else WAITV(2);   // stores only remain
        }
        __builtin_amdgcn_s_barrier();   // all waves' tile-i data now in LDS
        CFENCE();

        // ---- Compute: thread = (a, l) owns one bc slab ----
        const float* t1 = bufc + (a * TILE_ + l) * 27;
        const float* t2 = bufc + 4 * TILE_ * 27 + l * 27;
        float r1[27], r2[27];
        #pragma unroll
        for (int q = 0; q < 27; ++q) r1[q] = t1[q];
        #pragma unroll
        for (int q = 0; q < 27; ++q) r2[q] = t2[q];

        float acc[9];
        #pragma unroll
        for (int d = 0; d < 3; ++d) {
            #pragma unroll
            for (int g = 0; g < 3; ++g) {
                float s = 0.0f;
                #pragma unroll
                for (int e = 0; e < 3; ++e) {
                    #pragma unroll
                    for (int f = 0; f < 3; ++f) {
                        s += r1[d * 9 + e * 3 + f] * r2[e * 9 + f * 3 + g];
                    }
                }
                acc[d * 3 + g] = s * (1.0f / 3.0f);
            }
        }

        // ---- Stage output (dedicated region; prior tile's readers are
        //      guaranteed done: they read before the barrier above) ----
        #pragma unroll
        for (int q = 0; q < 9; ++q) {
            smem[OUT_OFF + (a * TILE_ + l) * 9 + q] = acc[q];
        }
        asm volatile("s_waitcnt lgkmcnt(0)" ::: "memory");  // ds_writes visible
        __builtin_amdgcn_s_barrier();
        CFENCE();

        // ---- Coalesced float4 write of tile i ----
        const float4* outs = (const float4*)(smem + OUT_OFF);
        const int tgt = t0 + i;
        for (int j = tid; j < 4 * OUT_TILE4; j += NTHREADS) {
            const int a2 = j / OUT_TILE4;
            const int r  = j - a2 * OUT_TILE4;
            Outv[a2 * OUT_A_STRIDE4 + (size_t)tgt * OUT_TILE4 + r] = outs[j];
        }
    }
}

extern "C" void kernel_launch(void* const* d_in, const int* in_sizes, int n_in,
                              void* d_out, int out_size, void* d_ws, size_t ws_size,
                              hipStream_t stream) {
    const float* T1 = (const float*)d_in[0];
    const float* T2 = (const float*)d_in[1];
    float* Out = (float*)d_out;
    prod_einsum_kernel<<<NBLOCKS, NTHREADS, 0, stream>>>(T1, T2, Out);
}

// Round 4
// 527.936 us; speedup vs baseline: 1.0049x; 1.0049x over previous
//
#include <hip/hip_runtime.h>

// out[a,bc,d,g] = (1/3) * sum_{e,f} T1[a,bc,d,e,f] * T2[bc,e,f,g]
// A=4, BC=786432; T1 slab 27 f32, T2 slab 27 f32, out slab 9 f32.
// ~538 MB irreducible traffic -> ~85us floor at 6.3 TB/s achievable.
//
// v4b: v4 with the nontemporal-store type fixed (native ext_vector_type
// instead of HIP float4 class). TILE_=32 / 128 threads -> 17.3 KB LDS
// -> ~9 blocks/CU (18 waves, 9 independent VMEM streams per CU). Theory:
// block-boundary load bubbles are covered by stream count, not per-wave
// pipelining (v3's explicit pipeline at 2 blocks/CU regressed).

typedef float f32x4 __attribute__((ext_vector_type(4)));

#define A_        4
#define BC_       786432
#define TILE_     32
#define NTHREADS  128
#define NBLOCKS   (BC_ / TILE_)      // 24576

#define SEG_BYTES    3456            // TILE_*27*4 per staged segment
#define SEG_FLOATS   864
#define CHUNK_BYTES  1024            // 64 lanes * 16B
#define TAIL_LANES   24              // 384B tail chunk (seg = 3*1024 + 384)
#define SLOTS_PER_WAVE 10            // 20 slots / 2 waves

#define T1_A_BYTES     84934656u     // BC_*27*4
#define OUT_A_STRIDE4  1769472       // BC_*9/4
#define OUT_TILE4      72            // TILE_*9/4
#define SMEM_FLOATS    4320          // 5 segments (4 T1 + 1 T2) = 17.28 KB

__device__ __forceinline__ void load_lds16(const void* g, void* l) {
    __builtin_amdgcn_global_load_lds(
        (const __attribute__((address_space(1))) void*)g,
        (__attribute__((address_space(3))) void*)l, 16, 0, 0);
}

__global__ __launch_bounds__(NTHREADS, 5)
void prod_einsum_kernel(const float* __restrict__ T1,
                        const float* __restrict__ T2,
                        float* __restrict__ Out) {
    // smem: [0, 3456) floats = 4 T1 segments; [3456, 4320) = T2 segment.
    // After compute, front of smem is reused as output staging (1152 floats).
    __shared__ float smem[SMEM_FLOATS];
    f32x4* Outv = (f32x4*)Out;

    const int tid  = threadIdx.x;
    const int lane = tid & 63;
    const int wave = tid >> 6;
    const int blk  = blockIdx.x;

    // ---- Stage 5 segments (4x T1-a, 1x T2) via async global->LDS ----
    {
        const char* t1b  = (const char*)T1 + (size_t)blk * SEG_BYTES;
        const char* t2b  = (const char*)T2 + (size_t)blk * SEG_BYTES;
        char*       lds0 = (char*)smem;
        const int c0 = wave * SLOTS_PER_WAVE;
        #pragma unroll
        for (int u = 0; u < SLOTS_PER_WAVE; ++u) {
            const int c = c0 + u;
            const int s = c >> 2;            // segment 0..4
            const int k = c & 3;             // slot within segment 0..3
            const char* gseg = (s < 4) ? (t1b + (size_t)s * T1_A_BYTES) : t2b;
            const char* gsrc = gseg + k * CHUNK_BYTES + lane * 16;
            char*       ldst = lds0 + s * SEG_BYTES + k * CHUNK_BYTES;
            if (k < 3) {
                load_lds16(gsrc, ldst);                  // full 1 KiB slot
            } else if (lane < TAIL_LANES) {
                load_lds16(gsrc, ldst);                  // 384 B tail
            }
        }
    }
    __syncthreads();

    // ---- Compute: thread = (a, l) owns one bc slab ----
    const int a = tid >> 5;                  // 0..3
    const int l = tid & 31;                  // 0..31
    const float* t1 = smem + (a * TILE_ + l) * 27;
    const float* t2 = smem + 4 * SEG_FLOATS + l * 27;

    float r1[27], r2[27];
    #pragma unroll
    for (int q = 0; q < 27; ++q) r1[q] = t1[q];
    #pragma unroll
    for (int q = 0; q < 27; ++q) r2[q] = t2[q];

    float acc[9];
    #pragma unroll
    for (int d = 0; d < 3; ++d) {
        #pragma unroll
        for (int g = 0; g < 3; ++g) {
            float s = 0.0f;
            #pragma unroll
            for (int e = 0; e < 3; ++e) {
                #pragma unroll
                for (int f = 0; f < 3; ++f) {
                    s += r1[d * 9 + e * 3 + f] * r2[e * 9 + f * 3 + g];
                }
            }
            acc[d * 3 + g] = s * (1.0f / 3.0f);
        }
    }

    __syncthreads();  // all LDS reads done; safe to overwrite front of smem

    // ---- Stage output: (a, l, 9) packed = 1152 floats ----
    #pragma unroll
    for (int q = 0; q < 9; ++q) {
        smem[(a * TILE_ + l) * 9 + q] = acc[q];
    }
    __syncthreads();

    // ---- Coalesced nontemporal write: 4 regions of 72 float4 = 288 ----
    const f32x4* smem4 = (const f32x4*)smem;
    for (int j = tid; j < 4 * OUT_TILE4; j += NTHREADS) {
        const int a2 = j / OUT_TILE4;
        const int r  = j - a2 * OUT_TILE4;
        __builtin_nontemporal_store(
            smem4[j], &Outv[a2 * OUT_A_STRIDE4 + (size_t)blk * OUT_TILE4 + r]);
    }
}

extern "C" void kernel_launch(void* const* d_in, const int* in_sizes, int n_in,
                              void* d_out, int out_size, void* d_ws, size_t ws_size,
                              hipStream_t stream) {
    const float* T1 = (const float*)d_in[0];
    const float* T2 = (const float*)d_in[1];
    float* Out = (float*)d_out;
    prod_einsum_kernel<<<NBLOCKS, NTHREADS, 0, stream>>>(T1, T2, Out);
}